// Round 1
// baseline (691.349 us; speedup 1.0000x reference)
//
#include <hip/hip_runtime.h>
#include <hip/hip_bf16.h>
#include <stdint.h>

#define NTOK   16384      // B*S = 4*4096
#define HID    2048
#define SELN   512
#define RESN   1536
#define YSZn   2048
#define RANKn  64
#define EPSf   1e-5f

typedef __bf16 bf16x8 __attribute__((ext_vector_type(8)));
typedef float f32x4 __attribute__((ext_vector_type(4)));

__device__ __forceinline__ unsigned short f2bf(float f) {
  unsigned u = __float_as_uint(f);
  u += 0x7fff + ((u >> 16) & 1);            // RNE
  return (unsigned short)(u >> 16);
}
__device__ __forceinline__ float bf2f(unsigned short h) {
  return __uint_as_float(((unsigned)h) << 16);
}
__device__ __forceinline__ float softplus_f(float x) {
  return fmaxf(x, 0.f) + log1pf(expf(-fabsf(x)));
}

#define GLD16(gp, lp) __builtin_amdgcn_global_load_lds( \
    (const __attribute__((address_space(1))) void*)(gp), \
    (__attribute__((address_space(3))) void*)(lp), 16, 0, 0)

// ---------------------------------------------------------------- convert
#define CY (NTOK * HID / 8)
#define CW (HID * YSZn / 8)
#define CD (RANKn * (HID + YSZn) / 8)
__global__ __launch_bounds__(256) void k_convert(
    const float* __restrict__ y, const float* __restrict__ Ww,
    const float* __restrict__ ddw,
    unsigned short* __restrict__ ybf, unsigned short* __restrict__ wbf,
    unsigned short* __restrict__ dbf) {
  int64_t stride = (int64_t)gridDim.x * blockDim.x;
  for (int64_t i = (int64_t)blockIdx.x * blockDim.x + threadIdx.x;
       i < CY + CW + CD; i += stride) {
    const float* src; unsigned short* dst;
    if (i < CY)            { src = y   + i * 8;            dst = ybf + i * 8; }
    else if (i < CY + CW)  { int64_t j = i - CY;       src = Ww  + j * 8; dst = wbf + j * 8; }
    else                   { int64_t j = i - CY - CW;  src = ddw + j * 8; dst = dbf + j * 8; }
    float4 a = ((const float4*)src)[0];
    float4 b = ((const float4*)src)[1];
    union { unsigned short u[8]; uint4 q; } o;
    o.u[0]=f2bf(a.x); o.u[1]=f2bf(a.y); o.u[2]=f2bf(a.z); o.u[3]=f2bf(a.w);
    o.u[4]=f2bf(b.x); o.u[5]=f2bf(b.y); o.u[6]=f2bf(b.z); o.u[7]=f2bf(b.w);
    *(uint4*)dst = o.q;
  }
}

// ---------------------------------------------------------------- wy GEMM
// C[t][h] = sum_k Y[t][k] * W[h][k]; M=16384 N=2048 K=2048; bf16 in/out.
// 128x128 tile, BK=32, 4 waves (2x2), m97 structure.
__global__ __launch_bounds__(256) void k_gemm_wy(
    const unsigned short* __restrict__ Y,
    const unsigned short* __restrict__ W,
    unsigned short* __restrict__ wy) {
  __shared__ unsigned short As[128 * 32];
  __shared__ unsigned short Bs[128 * 32];
  int bid = blockIdx.x;
  int swz = (bid & 7) * 256 + (bid >> 3);   // XCD-aware, 2048 % 8 == 0
  int mt = swz & 127, nt = swz >> 7;
  int m0 = mt * 128, n0 = nt * 128;
  int tid = threadIdx.x, w = tid >> 6, l = tid & 63;
  int wr = w >> 1, wc = w & 1;
  f32x4 acc[4][4] = {};

  int off0 = w * 1024 + l * 16;
  int r0 = off0 >> 6, kb0 = off0 & 63;
  int off1 = off0 + 4096;
  int r1 = off1 >> 6, kb1 = off1 & 63;
  const char* Ab = (const char*)Y;
  const char* Bb = (const char*)W;

  for (int kt = 0; kt < 64; ++kt) {
    int k0 = kt * 32;
    GLD16(Ab + ((size_t)(m0 + r0) * HID + k0) * 2 + kb0, (char*)As + w * 1024);
    GLD16(Ab + ((size_t)(m0 + r1) * HID + k0) * 2 + kb1, (char*)As + w * 1024 + 4096);
    GLD16(Bb + ((size_t)(n0 + r0) * HID + k0) * 2 + kb0, (char*)Bs + w * 1024);
    GLD16(Bb + ((size_t)(n0 + r1) * HID + k0) * 2 + kb1, (char*)Bs + w * 1024 + 4096);
    __syncthreads();                        // drains vmcnt: staging visible
    bf16x8 af[4], bv[4];
    #pragma unroll
    for (int mi = 0; mi < 4; ++mi) {
      int row = wr * 64 + mi * 16 + (l & 15);
      af[mi] = *reinterpret_cast<const bf16x8*>(&As[row * 32 + ((l >> 4) * 8)]);
    }
    #pragma unroll
    for (int ni = 0; ni < 4; ++ni) {
      int row = wc * 64 + ni * 16 + (l & 15);
      bv[ni] = *reinterpret_cast<const bf16x8*>(&Bs[row * 32 + ((l >> 4) * 8)]);
    }
    #pragma unroll
    for (int mi = 0; mi < 4; ++mi)
      #pragma unroll
      for (int ni = 0; ni < 4; ++ni)
        acc[mi][ni] = __builtin_amdgcn_mfma_f32_16x16x32_bf16(af[mi], bv[ni], acc[mi][ni], 0, 0, 0);
    if (kt < 63) __syncthreads();           // LDS reads done before restage
  }
  #pragma unroll
  for (int mi = 0; mi < 4; ++mi)
    #pragma unroll
    for (int ni = 0; ni < 4; ++ni) {
      int row = m0 + wr * 64 + mi * 16 + ((l >> 4) * 4);
      int col = n0 + wc * 64 + ni * 16 + (l & 15);
      #pragma unroll
      for (int rg = 0; rg < 4; ++rg)
        wy[(size_t)(row + rg) * HID + col] = f2bf(acc[mi][ni][rg]);
    }
}

// ---------------------------------------------------------------- layernorm
__global__ __launch_bounds__(256) void k_ln(
    const float* __restrict__ hidden,
    const float* __restrict__ sg, const float* __restrict__ sb,
    const float* __restrict__ rg, const float* __restrict__ rb,
    unsigned short* __restrict__ normed) {
  int tok = blockIdx.x, tid = threadIdx.x;
  const float* x = hidden + (size_t)tok * HID;
  float4 a = ((const float4*)x)[tid * 2];
  float4 b = ((const float4*)x)[tid * 2 + 1];
  float v[8] = {a.x, a.y, a.z, a.w, b.x, b.y, b.z, b.w};
  float s = 0.f, ss = 0.f;
  #pragma unroll
  for (int j = 0; j < 8; ++j) { s += v[j]; ss += v[j] * v[j]; }
  #pragma unroll
  for (int off = 32; off > 0; off >>= 1) {
    s  += __shfl_xor(s, off);
    ss += __shfl_xor(ss, off);
  }
  __shared__ float ps[4], pss[4];
  int w = tid >> 6;
  if ((tid & 63) == 0) { ps[w] = s; pss[w] = ss; }
  __syncthreads();
  float mu, rstd; const float* gam; const float* bet; int cb;
  if (tid < 64) {   // wave 0 owns SEL (elems 0..511)
    float S = ps[0], SS = pss[0];
    mu = S * (1.f / 512.f);
    rstd = rsqrtf(SS * (1.f / 512.f) - mu * mu + EPSf);
    gam = sg; bet = sb; cb = tid * 8;
  } else {          // waves 1-3 own RES (512..2047)
    float S = ps[1] + ps[2] + ps[3], SS = pss[1] + pss[2] + pss[3];
    mu = S * (1.f / 1536.f);
    rstd = rsqrtf(SS * (1.f / 1536.f) - mu * mu + EPSf);
    gam = rg; bet = rb; cb = tid * 8 - 512;
  }
  union { unsigned short u[8]; uint4 q; } o;
  #pragma unroll
  for (int j = 0; j < 8; ++j)
    o.u[j] = f2bf((v[j] - mu) * rstd * gam[cb + j] + bet[cb + j]);
  *(uint4*)&normed[(size_t)tok * HID + tid * 8] = o.q;
}

// ---------------------------------------------------------------- low GEMM
// low[t][r] = sum_c cat[t][c]*dd_w[r][c]; cat = [normed | y]; M=16384 N=64 K=4096.
// 64x64 tile, BK=64, 4 waves each owning 16 rows.
__global__ __launch_bounds__(256) void k_gemm_low(
    const unsigned short* __restrict__ normed,
    const unsigned short* __restrict__ ybf,
    const unsigned short* __restrict__ ddw,
    float* __restrict__ low) {
  __shared__ unsigned short As[64 * 64];
  __shared__ unsigned short Bs[64 * 64];
  int m0 = blockIdx.x * 64;
  int tid = threadIdx.x, w = tid >> 6, l = tid & 63;
  f32x4 acc[4] = {};
  int off0 = w * 1024 + l * 16;
  int r0 = off0 >> 7, kb0 = off0 & 127;
  int off1 = off0 + 4096;
  int r1 = off1 >> 7, kb1 = off1 & 127;

  for (int kt = 0; kt < 64; ++kt) {
    const char* Asrc = (const char*)((kt < 32) ? normed : ybf);
    int k0 = (kt & 31) * 64;
    GLD16(Asrc + ((size_t)(m0 + r0) * HID + k0) * 2 + kb0, (char*)As + w * 1024);
    GLD16(Asrc + ((size_t)(m0 + r1) * HID + k0) * 2 + kb1, (char*)As + w * 1024 + 4096);
    GLD16((const char*)ddw + ((size_t)r0 * 4096 + kt * 64) * 2 + kb0, (char*)Bs + w * 1024);
    GLD16((const char*)ddw + ((size_t)r1 * 4096 + kt * 64) * 2 + kb1, (char*)Bs + w * 1024 + 4096);
    __syncthreads();
    #pragma unroll
    for (int kk = 0; kk < 2; ++kk) {
      bf16x8 af = *reinterpret_cast<const bf16x8*>(
          &As[(w * 16 + (l & 15)) * 64 + kk * 32 + (l >> 4) * 8]);
      #pragma unroll
      for (int ni = 0; ni < 4; ++ni) {
        bf16x8 bv = *reinterpret_cast<const bf16x8*>(
            &Bs[(ni * 16 + (l & 15)) * 64 + kk * 32 + (l >> 4) * 8]);
        acc[ni] = __builtin_amdgcn_mfma_f32_16x16x32_bf16(af, bv, acc[ni], 0, 0, 0);
      }
    }
    if (kt < 63) __syncthreads();
  }
  #pragma unroll
  for (int ni = 0; ni < 4; ++ni) {
    int row = m0 + w * 16 + ((l >> 4) * 4);
    int col = ni * 16 + (l & 15);
    #pragma unroll
    for (int rg = 0; rg < 4; ++rg)
      low[(size_t)(row + rg) * 64 + col] = acc[ni][rg];
  }
}

// ---------------------------------------------------------------- delta + mix
// 512 threads: thread d owns channel d (du_w row in regs), 8 tokens/block.
__global__ __launch_bounds__(512) void k_final(
    const float* __restrict__ hidden,
    const unsigned short* __restrict__ wy,
    const float* __restrict__ low,
    const float* __restrict__ A,
    const float* __restrict__ duw,
    const float* __restrict__ dub,
    float* __restrict__ out) {
  __shared__ float slow[8][64];
  int t0 = blockIdx.x * 8;
  int tid = threadIdx.x;
  slow[tid >> 6][tid & 63] = low[(size_t)t0 * 64 + tid];
  __syncthreads();

  int d = tid;                              // 0..511
  float aneg = -softplus_f(A[d]);
  float dubv = dub[d];
  float wrow[64];
  #pragma unroll
  for (int r4 = 0; r4 < 16; ++r4) {
    float4 t = *(const float4*)&duw[(size_t)d * 64 + r4 * 4];
    wrow[r4 * 4 + 0] = t.x; wrow[r4 * 4 + 1] = t.y;
    wrow[r4 * 4 + 2] = t.z; wrow[r4 * 4 + 3] = t.w;
  }
  #pragma unroll 1
  for (int tk = 0; tk < 8; ++tk) {
    float acc = dubv;
    #pragma unroll
    for (int r = 0; r < 64; ++r) acc += wrow[r] * slow[tk][r];
    float delta = softplus_f(acc);
    float abar = expf(delta * aneg);
    float bbar = (abar - 1.f) / aneg;
    size_t base = (size_t)(t0 + tk) * HID;
    float selh = hidden[base + d];
    float sely = bf2f(wy[base + d]);
    out[base + d] = abar * selh + bbar * sely;
  }
  // residual half: out[c] = res_h + res_y, c in [512,2048)
  for (int i = tid; i < 8 * 384; i += 512) {
    int tk = i / 384, j = i - tk * 384;
    size_t base = (size_t)(t0 + tk) * HID + 512 + (size_t)j * 4;
    float4 h4 = *(const float4*)&hidden[base];
    ushort4 w4 = *(const ushort4*)&wy[base];
    float4 o;
    o.x = h4.x + bf2f(w4.x);
    o.y = h4.y + bf2f(w4.y);
    o.z = h4.z + bf2f(w4.z);
    o.w = h4.w + bf2f(w4.w);
    *(float4*)&out[base] = o;
  }
}

// ---------------------------------------------------------------- launch
extern "C" void kernel_launch(void* const* d_in, const int* in_sizes, int n_in,
                              void* d_out, int out_size, void* d_ws, size_t ws_size,
                              hipStream_t stream) {
  (void)in_sizes; (void)n_in; (void)out_size; (void)ws_size;
  const float* hidden = (const float*)d_in[0];
  const float* y      = (const float*)d_in[1];
  const float* A      = (const float*)d_in[2];
  const float* Ww     = (const float*)d_in[3];
  const float* ddw    = (const float*)d_in[4];
  const float* duw    = (const float*)d_in[5];
  const float* dub    = (const float*)d_in[6];
  const float* sg     = (const float*)d_in[7];
  const float* sb     = (const float*)d_in[8];
  const float* rg     = (const float*)d_in[9];
  const float* rb     = (const float*)d_in[10];
  float* out = (float*)d_out;
  char* ws = (char*)d_ws;
  // ws layout (bytes): 214,433,792 total
  unsigned short* ybf  = (unsigned short*)(ws);               //  67,108,864
  unsigned short* wbf  = (unsigned short*)(ws + 67108864);    //   8,388,608
  unsigned short* dbf  = (unsigned short*)(ws + 75497472);    //     524,288
  unsigned short* wybf = (unsigned short*)(ws + 76021760);    //  67,108,864
  unsigned short* nrm  = (unsigned short*)(ws + 143130624);   //  67,108,864
  float*          low  = (float*)(ws + 210239488);            //   4,194,304

  hipLaunchKernelGGL(k_convert,  dim3(2048),  dim3(256), 0, stream, y, Ww, ddw, ybf, wbf, dbf);
  hipLaunchKernelGGL(k_gemm_wy,  dim3(2048),  dim3(256), 0, stream, ybf, wbf, wybf);
  hipLaunchKernelGGL(k_ln,       dim3(16384), dim3(256), 0, stream, hidden, sg, sb, rg, rb, nrm);
  hipLaunchKernelGGL(k_gemm_low, dim3(256),   dim3(256), 0, stream, nrm, ybf, dbf, low);
  hipLaunchKernelGGL(k_final,    dim3(2048),  dim3(512), 0, stream, hidden, wybf, low, A, duw, dub, out);
}

// Round 3
// 630.995 us; speedup vs baseline: 1.0956x; 1.0956x over previous
//
#include <hip/hip_runtime.h>
#include <hip/hip_bf16.h>
#include <stdint.h>

#define NTOK   16384      // B*S = 4*4096
#define HID    2048
#define SELN   512
#define YSZn   2048
#define EPSf   1e-5f

typedef __bf16 bf16x8 __attribute__((ext_vector_type(8)));
typedef float f32x4 __attribute__((ext_vector_type(4)));

__device__ __forceinline__ unsigned short f2bf(float f) {
  unsigned u = __float_as_uint(f);
  u += 0x7fff + ((u >> 16) & 1);            // RNE
  return (unsigned short)(u >> 16);
}
__device__ __forceinline__ float bf2f(unsigned short h) {
  return __uint_as_float(((unsigned)h) << 16);
}
__device__ __forceinline__ float softplus_f(float x) {
  return fmaxf(x, 0.f) + log1pf(expf(-fabsf(x)));
}

#define GLD16(gp, lp) __builtin_amdgcn_global_load_lds( \
    (const __attribute__((address_space(1))) void*)(gp), \
    (__attribute__((address_space(3))) void*)(lp), 16, 0, 0)
#define BAR()  __builtin_amdgcn_s_barrier()
#define PRIO1() __builtin_amdgcn_s_setprio(1)
#define PRIO0() __builtin_amdgcn_s_setprio(0)

// ---------------------------------------------------------------- convert
#define CY (NTOK * HID / 8)
#define CW (HID * YSZn / 8)
#define CD (64 * (HID + YSZn) / 8)
__global__ __launch_bounds__(256) void k_convert(
    const float* __restrict__ y, const float* __restrict__ Ww,
    const float* __restrict__ ddw,
    unsigned short* __restrict__ ybf, unsigned short* __restrict__ wbf,
    unsigned short* __restrict__ dbf) {
  int64_t stride = (int64_t)gridDim.x * blockDim.x;
  for (int64_t i = (int64_t)blockIdx.x * blockDim.x + threadIdx.x;
       i < CY + CW + CD; i += stride) {
    const float* src; unsigned short* dst;
    if (i < CY)            { src = y   + i * 8;            dst = ybf + i * 8; }
    else if (i < CY + CW)  { int64_t j = i - CY;       src = Ww  + j * 8; dst = wbf + j * 8; }
    else                   { int64_t j = i - CY - CW;  src = ddw + j * 8; dst = dbf + j * 8; }
    float4 a = ((const float4*)src)[0];
    float4 b = ((const float4*)src)[1];
    union { unsigned short u[8]; uint4 q; } o;
    o.u[0]=f2bf(a.x); o.u[1]=f2bf(a.y); o.u[2]=f2bf(a.z); o.u[3]=f2bf(a.w);
    o.u[4]=f2bf(b.x); o.u[5]=f2bf(b.y); o.u[6]=f2bf(b.z); o.u[7]=f2bf(b.w);
    *(uint4*)dst = o.q;
  }
}

// ---------------------------------------------------------------- wy GEMM
// C[t][h] = sum_k Y[t][k]*W[h][k]; M=16384 N=2048 K=2048.
// 256x256 tile, BK=64, 8 waves (2Mx4N), 8-phase schedule, st_16x32 swizzle.
// Epilogue: cols<512 -> compact bf16 wysel; cols>=512 -> out = hidden + acc.
// LDS map: A buf0 @0, A buf1 @32768, B buf0 @65536, B buf1 @98304.
// Each 32KB buf = two 16KB K-half regions (k 0..31 / 32..63), 256 rows each.
// Region layout: 16 subtiles of [16 rows][32 k] = 1024B, swizzled:
//   off = (row>>4)*1024 + (((row&15)*64 + (k&31)*2) ^ (((row>>3)&1)<<5))
__global__ __launch_bounds__(512, 2) void k_gemm_wy(
    const unsigned short* __restrict__ Y,
    const unsigned short* __restrict__ W,
    const float* __restrict__ hidden,
    unsigned short* __restrict__ wysel,
    float* __restrict__ out) {
  __shared__ char lds[131072];
  int bid = blockIdx.x;
  int nt = bid & 7, mt = bid >> 3;          // XCD keeps one B-panel (1MB) in L2
  int m0 = mt * 256, n0 = nt * 256;
  int tid = threadIdx.x;
  int l = tid & 63, w = tid >> 6;
  int wr = w >> 2, wc = w & 3;

  // staging decode: load i of a half-tile -> linear LDS byte L = i*8192 + tid*16
  int rowS[2], colS[2];
  #pragma unroll
  for (int i = 0; i < 2; ++i) {
    int L  = i * 8192 + tid * 16;
    int rb = L >> 10;
    int b  = L & 1023;
    int rr = (b >> 6) & 15;
    int cb = (b & 63) ^ ((rr >> 3) << 5);   // inverse swizzle -> source col
    rowS[i] = rb * 16 + rr;
    colS[i] = cb >> 1;
  }
  const unsigned short* aSrc0 = Y + (size_t)(m0 + rowS[0]) * HID + colS[0];
  const unsigned short* aSrc1 = Y + (size_t)(m0 + rowS[1]) * HID + colS[1];
  const unsigned short* bSrc0 = W + (size_t)(n0 + rowS[0]) * HID + colS[0];
  const unsigned short* bSrc1 = W + (size_t)(n0 + rowS[1]) * HID + colS[1];

  int inner = (((l & 15) * 64) + ((l >> 4) * 16)) ^ (((l >> 3) & 1) << 5);
  const char* ldsp = (const char*)lds;

  f32x4 acc[8][4] = {};

#define STAGE_A(kt, kh, bb) do { \
    GLD16(aSrc0 + (size_t)(kt) * 64 + (kh) * 32, lds + (bb) + (kh) * 16384 + w * 1024); \
    GLD16(aSrc1 + (size_t)(kt) * 64 + (kh) * 32, lds + (bb) + (kh) * 16384 + 8192 + w * 1024); \
  } while (0)
#define STAGE_B(kt, kh, bb) do { \
    GLD16(bSrc0 + (size_t)(kt) * 64 + (kh) * 32, lds + 65536 + (bb) + (kh) * 16384 + w * 1024); \
    GLD16(bSrc1 + (size_t)(kt) * 64 + (kh) * 32, lds + 65536 + (bb) + (kh) * 16384 + 8192 + w * 1024); \
  } while (0)

  auto rdA = [&](int cbase, int kk, int mg, bf16x8* af) {
    #pragma unroll
    for (int mi = 0; mi < 4; ++mi)
      af[mi] = *(const bf16x8*)(ldsp + cbase + kk * 16384 +
                                (mg * 8 + wr * 4 + mi) * 1024 + inner);
  };
  auto rdB = [&](int cbase, int kk, bf16x8* bv) {
    #pragma unroll
    for (int ni = 0; ni < 4; ++ni)
      bv[ni] = *(const bf16x8*)(ldsp + 65536 + cbase + kk * 16384 +
                                (wc * 4 + ni) * 1024 + inner);
  };

  // prologue: stage K-tile 0 (4 half-tiles) into buf0
  STAGE_A(0, 0, 0); STAGE_B(0, 0, 0); STAGE_A(0, 1, 0); STAGE_B(0, 1, 0);
  asm volatile("s_waitcnt vmcnt(4)");       // A_k0,B_k0 landed
  BAR();

  int buf = 0;
  for (int kt = 0; kt < 32; ++kt) {
    int cb = buf * 32768;                   // compute buffer
    int sb = 32768 - cb;                    // stage buffer
    bool last = (kt == 31);
    bf16x8 af[4], bv[4];

    // phase 0: (mg0, kk0) + B(kk0); stage A_k0(kt+1)
    rdA(cb, 0, 0, af); rdB(cb, 0, bv);
    if (!last) STAGE_A(kt + 1, 0, sb);
    BAR();
    asm volatile("s_waitcnt lgkmcnt(0)");
    PRIO1();
    #pragma unroll
    for (int mi = 0; mi < 4; ++mi)
      #pragma unroll
      for (int ni = 0; ni < 4; ++ni)
        acc[mi][ni] = __builtin_amdgcn_mfma_f32_16x16x32_bf16(af[mi], bv[ni], acc[mi][ni], 0, 0, 0);
    PRIO0();
    BAR();

    // phase 1: (mg1, kk0), reuse bv; stage B_k0(kt+1); counted wait
    rdA(cb, 0, 1, af);
    if (!last) STAGE_B(kt + 1, 0, sb);
    BAR();
    asm volatile("s_waitcnt lgkmcnt(0)");
    PRIO1();
    #pragma unroll
    for (int mi = 0; mi < 4; ++mi)
      #pragma unroll
      for (int ni = 0; ni < 4; ++ni)
        acc[4 + mi][ni] = __builtin_amdgcn_mfma_f32_16x16x32_bf16(af[mi], bv[ni], acc[4 + mi][ni], 0, 0, 0);
    PRIO0();
    if (last) asm volatile("s_waitcnt vmcnt(0)");   // drain for final K-half
    else      asm volatile("s_waitcnt vmcnt(4)");   // A_k1(kt),B_k1(kt) landed
    BAR();

    // phase 2: (mg0, kk1) + B(kk1); stage A_k1(kt+1)
    rdA(cb, 1, 0, af); rdB(cb, 1, bv);
    if (!last) STAGE_A(kt + 1, 1, sb);
    BAR();
    asm volatile("s_waitcnt lgkmcnt(0)");
    PRIO1();
    #pragma unroll
    for (int mi = 0; mi < 4; ++mi)
      #pragma unroll
      for (int ni = 0; ni < 4; ++ni)
        acc[mi][ni] = __builtin_amdgcn_mfma_f32_16x16x32_bf16(af[mi], bv[ni], acc[mi][ni], 0, 0, 0);
    PRIO0();
    BAR();

    // phase 3: (mg1, kk1), reuse bv; stage B_k1(kt+1); counted wait
    rdA(cb, 1, 1, af);
    if (!last) STAGE_B(kt + 1, 1, sb);
    BAR();
    asm volatile("s_waitcnt lgkmcnt(0)");
    PRIO1();
    #pragma unroll
    for (int mi = 0; mi < 4; ++mi)
      #pragma unroll
      for (int ni = 0; ni < 4; ++ni)
        acc[4 + mi][ni] = __builtin_amdgcn_mfma_f32_16x16x32_bf16(af[mi], bv[ni], acc[4 + mi][ni], 0, 0, 0);
    PRIO0();
    if (!last) asm volatile("s_waitcnt vmcnt(4)");  // A_k0(kt+1),B_k0(kt+1) landed
    BAR();

    buf ^= 1;
  }

  // epilogue: sel tiles -> compact bf16; res tiles -> fused residual add (f32)
  if (nt < 2) {
    #pragma unroll
    for (int mg = 0; mg < 2; ++mg)
      #pragma unroll
      for (int mi = 0; mi < 4; ++mi)
        #pragma unroll
        for (int ni = 0; ni < 4; ++ni) {
          int row = m0 + mg * 128 + wr * 64 + mi * 16 + ((l >> 4) * 4);
          int col = n0 + wc * 64 + ni * 16 + (l & 15);
          #pragma unroll
          for (int rg = 0; rg < 4; ++rg)
            wysel[(size_t)(row + rg) * SELN + col] = f2bf(acc[mg * 4 + mi][ni][rg]);
        }
  } else {
    #pragma unroll
    for (int mg = 0; mg < 2; ++mg)
      #pragma unroll
      for (int mi = 0; mi < 4; ++mi)
        #pragma unroll
        for (int ni = 0; ni < 4; ++ni) {
          int row = m0 + mg * 128 + wr * 64 + mi * 16 + ((l >> 4) * 4);
          int col = n0 + wc * 64 + ni * 16 + (l & 15);
          #pragma unroll
          for (int rg = 0; rg < 4; ++rg) {
            size_t idx = (size_t)(row + rg) * HID + col;
            out[idx] = hidden[idx] + acc[mg * 4 + mi][ni][rg];
          }
        }
  }
#undef STAGE_A
#undef STAGE_B
}

// ---------------------------------------------------------------- layernorm
__global__ __launch_bounds__(256) void k_ln(
    const float* __restrict__ hidden,
    const float* __restrict__ sg, const float* __restrict__ sb,
    const float* __restrict__ rg, const float* __restrict__ rb,
    unsigned short* __restrict__ normed) {
  int tok = blockIdx.x, tid = threadIdx.x;
  const float* x = hidden + (size_t)tok * HID;
  float4 a = ((const float4*)x)[tid * 2];
  float4 b = ((const float4*)x)[tid * 2 + 1];
  float v[8] = {a.x, a.y, a.z, a.w, b.x, b.y, b.z, b.w};
  float s = 0.f, ss = 0.f;
  #pragma unroll
  for (int j = 0; j < 8; ++j) { s += v[j]; ss += v[j] * v[j]; }
  #pragma unroll
  for (int off = 32; off > 0; off >>= 1) {
    s  += __shfl_xor(s, off);
    ss += __shfl_xor(ss, off);
  }
  __shared__ float ps[4], pss[4];
  int w = tid >> 6;
  if ((tid & 63) == 0) { ps[w] = s; pss[w] = ss; }
  __syncthreads();
  float mu, rstd; const float* gam; const float* bet; int cb;
  if (tid < 64) {
    float S = ps[0], SS = pss[0];
    mu = S * (1.f / 512.f);
    rstd = rsqrtf(SS * (1.f / 512.f) - mu * mu + EPSf);
    gam = sg; bet = sb; cb = tid * 8;
  } else {
    float S = ps[1] + ps[2] + ps[3], SS = pss[1] + pss[2] + pss[3];
    mu = S * (1.f / 1536.f);
    rstd = rsqrtf(SS * (1.f / 1536.f) - mu * mu + EPSf);
    gam = rg; bet = rb; cb = tid * 8 - 512;
  }
  union { unsigned short u[8]; uint4 q; } o;
  #pragma unroll
  for (int j = 0; j < 8; ++j)
    o.u[j] = f2bf((v[j] - mu) * rstd * gam[cb + j] + bet[cb + j]);
  *(uint4*)&normed[(size_t)tok * HID + tid * 8] = o.q;
}

// ---------------------------------------------------------------- low GEMM
// low[t][r] = sum_c cat[t][c]*dd_w[r][c]; cat=[normed|y]; M=16384 N=64 K=4096.
// 64x64 tile, BK=64, double-buffered, swizzled LDS (same st_16x32 scheme).
// LDS per buf (16KB): A @0 (8 subtiles: (row>>4)*2+kk), B @8192 ((rank>>4)*2+kk).
__global__ __launch_bounds__(256) void k_gemm_low(
    const unsigned short* __restrict__ normed,
    const unsigned short* __restrict__ ybf,
    const unsigned short* __restrict__ ddw,
    float* __restrict__ low) {
  __shared__ char lds[32768];
  int m0 = blockIdx.x * 64;
  int tid = threadIdx.x, w = tid >> 6, l = tid & 63;
  f32x4 acc[4] = {};

  int rowS[2], colS[2];
  #pragma unroll
  for (int i = 0; i < 2; ++i) {
    int L  = i * 4096 + tid * 16;
    int sbt = L >> 10;                      // subtile 0..7
    int b  = L & 1023;
    int rr = (b >> 6) & 15;
    rowS[i] = (sbt >> 1) * 16 + rr;
    colS[i] = (sbt & 1) * 32 + (((b & 63) ^ ((rr >> 3) << 5)) >> 1);
  }
  int inner = (((l & 15) * 64) + ((l >> 4) * 16)) ^ (((l >> 3) & 1) << 5);
  const char* ldsp = (const char*)lds;

  auto stage = [&](const unsigned short* As_, int kt, int bb) {
    int k0 = (kt & 31) * 64;
    GLD16(As_ + (size_t)(m0 + rowS[0]) * HID + k0 + colS[0], lds + bb + w * 1024);
    GLD16(As_ + (size_t)(m0 + rowS[1]) * HID + k0 + colS[1], lds + bb + 4096 + w * 1024);
    GLD16(ddw + (size_t)rowS[0] * 4096 + kt * 64 + colS[0], lds + bb + 8192 + w * 1024);
    GLD16(ddw + (size_t)rowS[1] * 4096 + kt * 64 + colS[1], lds + bb + 8192 + 4096 + w * 1024);
  };

  stage(normed, 0, 0);
  asm volatile("s_waitcnt vmcnt(0)");
  BAR();
  int buf = 0;
  for (int kt = 0; kt < 64; ++kt) {
    int cb = buf * 16384, sb = 16384 - cb;
    if (kt < 63) stage((kt + 1 < 32) ? normed : ybf, kt + 1, sb);
    bf16x8 af0 = *(const bf16x8*)(ldsp + cb + (w * 2 + 0) * 1024 + inner);
    bf16x8 af1 = *(const bf16x8*)(ldsp + cb + (w * 2 + 1) * 1024 + inner);
    #pragma unroll
    for (int ni = 0; ni < 4; ++ni) {
      bf16x8 b0 = *(const bf16x8*)(ldsp + cb + 8192 + (ni * 2 + 0) * 1024 + inner);
      acc[ni] = __builtin_amdgcn_mfma_f32_16x16x32_bf16(af0, b0, acc[ni], 0, 0, 0);
    }
    #pragma unroll
    for (int ni = 0; ni < 4; ++ni) {
      bf16x8 b1 = *(const bf16x8*)(ldsp + cb + 8192 + (ni * 2 + 1) * 1024 + inner);
      acc[ni] = __builtin_amdgcn_mfma_f32_16x16x32_bf16(af1, b1, acc[ni], 0, 0, 0);
    }
    if (kt < 63) asm volatile("s_waitcnt vmcnt(0)");
    BAR();
    buf ^= 1;
  }
  #pragma unroll
  for (int ni = 0; ni < 4; ++ni) {
    int row = m0 + w * 16 + ((l >> 4) * 4);
    int col = ni * 16 + (l & 15);
    #pragma unroll
    for (int rg = 0; rg < 4; ++rg)
      low[(size_t)(row + rg) * 64 + col] = acc[ni][rg];
  }
}

// ---------------------------------------------------------------- delta + mix (sel only)
__global__ __launch_bounds__(512) void k_final(
    const float* __restrict__ hidden,
    const unsigned short* __restrict__ wysel,
    const float* __restrict__ low,
    const float* __restrict__ A,
    const float* __restrict__ duw,
    const float* __restrict__ dub,
    float* __restrict__ out) {
  __shared__ float slow[8][64];
  int t0 = blockIdx.x * 8;
  int tid = threadIdx.x;
  slow[tid >> 6][tid & 63] = low[(size_t)t0 * 64 + tid];
  __syncthreads();

  int d = tid;                              // 0..511
  float aneg = -softplus_f(A[d]);
  float dubv = dub[d];
  float wrow[64];
  #pragma unroll
  for (int r4 = 0; r4 < 16; ++r4) {
    float4 t = *(const float4*)&duw[(size_t)d * 64 + r4 * 4];
    wrow[r4 * 4 + 0] = t.x; wrow[r4 * 4 + 1] = t.y;
    wrow[r4 * 4 + 2] = t.z; wrow[r4 * 4 + 3] = t.w;
  }
  #pragma unroll 1
  for (int tk = 0; tk < 8; ++tk) {
    float acc = dubv;
    #pragma unroll
    for (int r = 0; r < 64; ++r) acc += wrow[r] * slow[tk][r];
    float delta = softplus_f(acc);
    float abar = expf(delta * aneg);
    float bbar = (abar - 1.f) / aneg;
    size_t tokb = (size_t)(t0 + tk);
    float selh = hidden[tokb * HID + d];
    float sely = bf2f(wysel[tokb * SELN + d]);
    out[tokb * HID + d] = abar * selh + bbar * sely;
  }
}

// ---------------------------------------------------------------- launch
extern "C" void kernel_launch(void* const* d_in, const int* in_sizes, int n_in,
                              void* d_out, int out_size, void* d_ws, size_t ws_size,
                              hipStream_t stream) {
  (void)in_sizes; (void)n_in; (void)out_size; (void)ws_size;
  const float* hidden = (const float*)d_in[0];
  const float* y      = (const float*)d_in[1];
  const float* A      = (const float*)d_in[2];
  const float* Ww     = (const float*)d_in[3];
  const float* ddw    = (const float*)d_in[4];
  const float* duw    = (const float*)d_in[5];
  const float* dub    = (const float*)d_in[6];
  const float* sg     = (const float*)d_in[7];
  const float* sb     = (const float*)d_in[8];
  const float* rg     = (const float*)d_in[9];
  const float* rb     = (const float*)d_in[10];
  float* out = (float*)d_out;
  char* ws = (char*)d_ws;
  // ws layout (bytes):
  unsigned short* ybf   = (unsigned short*)(ws);              //  67,108,864
  unsigned short* wbf   = (unsigned short*)(ws + 67108864);   //   8,388,608
  unsigned short* dbf   = (unsigned short*)(ws + 75497472);   //     524,288
  unsigned short* wysel = (unsigned short*)(ws + 76021760);   //  16,777,216
  unsigned short* nrm   = (unsigned short*)(ws + 92798976);   //  67,108,864
  float*          low   = (float*)(ws + 159907840);           //   4,194,304

  hipLaunchKernelGGL(k_convert,  dim3(2048),  dim3(256), 0, stream, y, Ww, ddw, ybf, wbf, dbf);
  hipLaunchKernelGGL(k_gemm_wy,  dim3(512),   dim3(512), 0, stream, ybf, wbf, hidden, wysel, out);
  hipLaunchKernelGGL(k_ln,       dim3(16384), dim3(256), 0, stream, hidden, sg, sb, rg, rb, nrm);
  hipLaunchKernelGGL(k_gemm_low, dim3(256),   dim3(256), 0, stream, nrm, ybf, dbf, low);
  hipLaunchKernelGGL(k_final,    dim3(2048),  dim3(512), 0, stream, hidden, wysel, low, A, duw, dub, out);
}

// Round 9
// 596.834 us; speedup vs baseline: 1.1584x; 1.0572x over previous
//
#include <hip/hip_runtime.h>
#include <hip/hip_bf16.h>
#include <stdint.h>

#define NTOK   16384      // B*S = 4*4096
#define HID    2048
#define SELN   512
#define YSZn   2048
#define EPSf   1e-5f

typedef __bf16 bf16x8 __attribute__((ext_vector_type(8)));
typedef float f32x4 __attribute__((ext_vector_type(4)));

__device__ __forceinline__ unsigned short f2bf(float f) {
  unsigned u = __float_as_uint(f);
  u += 0x7fff + ((u >> 16) & 1);            // RNE
  return (unsigned short)(u >> 16);
}
__device__ __forceinline__ float bf2f(unsigned short h) {
  return __uint_as_float(((unsigned)h) << 16);
}
__device__ __forceinline__ float softplus_f(float x) {
  return fmaxf(x, 0.f) + log1pf(expf(-fabsf(x)));
}

#define GLD16(gp, lp) __builtin_amdgcn_global_load_lds( \
    (const __attribute__((address_space(1))) void*)(gp), \
    (__attribute__((address_space(3))) void*)(lp), 16, 0, 0)
#define BAR()  __builtin_amdgcn_s_barrier()
#define PRIO1() __builtin_amdgcn_s_setprio(1)
#define PRIO0() __builtin_amdgcn_s_setprio(0)

// ---------------------------------------------------------------- convert
#define CY (NTOK * HID / 8)
#define CW (HID * YSZn / 8)
#define CD (64 * (HID + YSZn) / 8)
__global__ __launch_bounds__(256) void k_convert(
    const float* __restrict__ y, const float* __restrict__ Ww,
    const float* __restrict__ ddw,
    unsigned short* __restrict__ ybf, unsigned short* __restrict__ wbf,
    unsigned short* __restrict__ dbf) {
  int64_t stride = (int64_t)gridDim.x * blockDim.x;
  for (int64_t i = (int64_t)blockIdx.x * blockDim.x + threadIdx.x;
       i < CY + CW + CD; i += stride) {
    const float* src; unsigned short* dst;
    if (i < CY)            { src = y   + i * 8;            dst = ybf + i * 8; }
    else if (i < CY + CW)  { int64_t j = i - CY;       src = Ww  + j * 8; dst = wbf + j * 8; }
    else                   { int64_t j = i - CY - CW;  src = ddw + j * 8; dst = dbf + j * 8; }
    float4 a = ((const float4*)src)[0];
    float4 b = ((const float4*)src)[1];
    union { unsigned short u[8]; uint4 q; } o;
    o.u[0]=f2bf(a.x); o.u[1]=f2bf(a.y); o.u[2]=f2bf(a.z); o.u[3]=f2bf(a.w);
    o.u[4]=f2bf(b.x); o.u[5]=f2bf(b.y); o.u[6]=f2bf(b.z); o.u[7]=f2bf(b.w);
    *(uint4*)dst = o.q;
  }
}

// ---------------------------------------------------------------- wy GEMM
// C[t][h] = sum_k Y[t][k]*W[h][k]; M=16384 N=2048 K=2048.
// 256x256 tile, BK=64, 8 waves (2Mx4N), 2 phases/K-tile (32 MFMA per
// barrier-pair, AITER-like density), st_16x32 swizzle, counted vmcnt(4).
// Epilogue: cols<512 -> compact bf16 wysel; cols>=512 -> out = hidden + acc.
// LDS map: A buf0 @0, A buf1 @32768, B buf0 @65536, B buf1 @98304.
// Each 32KB buf = two 16KB K-half regions (k 0..31 / 32..63), 256 rows each.
// Region layout: 16 subtiles of [16 rows][32 k] = 1024B, swizzled:
//   off = (row>>4)*1024 + (((row&15)*64 + (k&31)*2) ^ (((row>>3)&1)<<5))
__global__ __launch_bounds__(512, 1) void k_gemm_wy(
    const unsigned short* __restrict__ Y,
    const unsigned short* __restrict__ W,
    const float* __restrict__ hidden,
    unsigned short* __restrict__ wysel,
    float* __restrict__ out) {
  __shared__ char lds[131072];
  int bid = blockIdx.x;
  int nt = bid & 7, mt = bid >> 3;          // XCD keeps one B-panel (1MB) in L2
  int m0 = mt * 256, n0 = nt * 256;
  int tid = threadIdx.x;
  int l = tid & 63, w = tid >> 6;
  int wr = w >> 2, wc = w & 3;

  // staging decode: load i of a half-tile -> linear LDS byte L = i*8192 + tid*16
  int rowS[2], colS[2];
  #pragma unroll
  for (int i = 0; i < 2; ++i) {
    int L  = i * 8192 + tid * 16;
    int rb = L >> 10;
    int b  = L & 1023;
    int rr = (b >> 6) & 15;
    int cb = (b & 63) ^ ((rr >> 3) << 5);   // inverse swizzle -> source col
    rowS[i] = rb * 16 + rr;
    colS[i] = cb >> 1;
  }
  const unsigned short* aSrc0 = Y + (size_t)(m0 + rowS[0]) * HID + colS[0];
  const unsigned short* aSrc1 = Y + (size_t)(m0 + rowS[1]) * HID + colS[1];
  const unsigned short* bSrc0 = W + (size_t)(n0 + rowS[0]) * HID + colS[0];
  const unsigned short* bSrc1 = W + (size_t)(n0 + rowS[1]) * HID + colS[1];

  int inner = (((l & 15) * 64) + ((l >> 4) * 16)) ^ (((l >> 3) & 1) << 5);
  const char* ldsp = (const char*)lds;

  f32x4 acc[8][4] = {};

#define STAGE_A(kt, kh, bb) do { \
    GLD16(aSrc0 + (size_t)(kt) * 64 + (kh) * 32, lds + (bb) + (kh) * 16384 + w * 1024); \
    GLD16(aSrc1 + (size_t)(kt) * 64 + (kh) * 32, lds + (bb) + (kh) * 16384 + 8192 + w * 1024); \
  } while (0)
#define STAGE_B(kt, kh, bb) do { \
    GLD16(bSrc0 + (size_t)(kt) * 64 + (kh) * 32, lds + 65536 + (bb) + (kh) * 16384 + w * 1024); \
    GLD16(bSrc1 + (size_t)(kt) * 64 + (kh) * 32, lds + 65536 + (bb) + (kh) * 16384 + 8192 + w * 1024); \
  } while (0)

  // prologue: stage K-tile 0 (4 half-tiles) into buf0
  STAGE_A(0, 0, 0); STAGE_B(0, 0, 0); STAGE_A(0, 1, 0); STAGE_B(0, 1, 0);
  asm volatile("s_waitcnt vmcnt(4)");       // A_h0,B_h0 landed
  BAR();

  int buf = 0;
  for (int kt = 0; kt < 32; ++kt) {
    int cb = buf * 32768;                   // compute buffer
    int sb = 32768 - cb;                    // stage buffer
    bool last = (kt == 31);
    bf16x8 af[8], bv[4];

    // ---- phase 0: kk=0, all 8 M-frags x 4 N-frags = 32 MFMA
    #pragma unroll
    for (int mi = 0; mi < 8; ++mi)
      af[mi] = *(const bf16x8*)(ldsp + cb + ((mi >> 2) * 8 + wr * 4 + (mi & 3)) * 1024 + inner);
    #pragma unroll
    for (int ni = 0; ni < 4; ++ni)
      bv[ni] = *(const bf16x8*)(ldsp + 65536 + cb + (wc * 4 + ni) * 1024 + inner);
    if (!last) { STAGE_A(kt + 1, 0, sb); STAGE_B(kt + 1, 0, sb); }
    BAR();
    asm volatile("s_waitcnt lgkmcnt(0)");
    PRIO1();
    #pragma unroll
    for (int mi = 0; mi < 8; ++mi)
      #pragma unroll
      for (int ni = 0; ni < 4; ++ni)
        acc[mi][ni] = __builtin_amdgcn_mfma_f32_16x16x32_bf16(af[mi], bv[ni], acc[mi][ni], 0, 0, 0);
    PRIO0();
    // A_h1(kt),B_h1(kt) must land before phase 1 reads them
    if (last) asm volatile("s_waitcnt vmcnt(0)");
    else      asm volatile("s_waitcnt vmcnt(4)");
    BAR();

    // ---- phase 1: kk=1
    #pragma unroll
    for (int mi = 0; mi < 8; ++mi)
      af[mi] = *(const bf16x8*)(ldsp + cb + 16384 + ((mi >> 2) * 8 + wr * 4 + (mi & 3)) * 1024 + inner);
    #pragma unroll
    for (int ni = 0; ni < 4; ++ni)
      bv[ni] = *(const bf16x8*)(ldsp + 65536 + cb + 16384 + (wc * 4 + ni) * 1024 + inner);
    if (!last) { STAGE_A(kt + 1, 1, sb); STAGE_B(kt + 1, 1, sb); }
    BAR();
    asm volatile("s_waitcnt lgkmcnt(0)");
    PRIO1();
    #pragma unroll
    for (int mi = 0; mi < 8; ++mi)
      #pragma unroll
      for (int ni = 0; ni < 4; ++ni)
        acc[mi][ni] = __builtin_amdgcn_mfma_f32_16x16x32_bf16(af[mi], bv[ni], acc[mi][ni], 0, 0, 0);
    PRIO0();
    // A_h0(kt+1),B_h0(kt+1) must land before next phase 0 reads them
    if (!last) asm volatile("s_waitcnt vmcnt(4)");
    BAR();

    buf ^= 1;
  }

  // epilogue: sel tiles -> compact bf16; res tiles -> fused residual add (f32)
  if (nt < 2) {
    #pragma unroll
    for (int mg = 0; mg < 2; ++mg)
      #pragma unroll
      for (int mi = 0; mi < 4; ++mi)
        #pragma unroll
        for (int ni = 0; ni < 4; ++ni) {
          int row = m0 + mg * 128 + wr * 64 + mi * 16 + ((l >> 4) * 4);
          int col = n0 + wc * 64 + ni * 16 + (l & 15);
          #pragma unroll
          for (int rg = 0; rg < 4; ++rg)
            wysel[(size_t)(row + rg) * SELN + col] = f2bf(acc[mg * 4 + mi][ni][rg]);
        }
  } else {
    #pragma unroll
    for (int mg = 0; mg < 2; ++mg)
      #pragma unroll
      for (int mi = 0; mi < 4; ++mi)
        #pragma unroll
        for (int ni = 0; ni < 4; ++ni) {
          int row = m0 + mg * 128 + wr * 64 + mi * 16 + ((l >> 4) * 4);
          int col = n0 + wc * 64 + ni * 16 + (l & 15);
          #pragma unroll
          for (int rg = 0; rg < 4; ++rg) {
            size_t idx = (size_t)(row + rg) * HID + col;
            out[idx] = hidden[idx] + acc[mg * 4 + mi][ni][rg];
          }
        }
  }
#undef STAGE_A
#undef STAGE_B
}

// ---------------------------------------------------------------- layernorm
__global__ __launch_bounds__(256) void k_ln(
    const float* __restrict__ hidden,
    const float* __restrict__ sg, const float* __restrict__ sb,
    const float* __restrict__ rg, const float* __restrict__ rb,
    unsigned short* __restrict__ normed) {
  int tok = blockIdx.x, tid = threadIdx.x;
  const float* x = hidden + (size_t)tok * HID;
  float4 a = ((const float4*)x)[tid * 2];
  float4 b = ((const float4*)x)[tid * 2 + 1];
  float v[8] = {a.x, a.y, a.z, a.w, b.x, b.y, b.z, b.w};
  float s = 0.f, ss = 0.f;
  #pragma unroll
  for (int j = 0; j < 8; ++j) { s += v[j]; ss += v[j] * v[j]; }
  #pragma unroll
  for (int off = 32; off > 0; off >>= 1) {
    s  += __shfl_xor(s, off);
    ss += __shfl_xor(ss, off);
  }
  __shared__ float ps[4], pss[4];
  int w = tid >> 6;
  if ((tid & 63) == 0) { ps[w] = s; pss[w] = ss; }
  __syncthreads();
  float mu, rstd; const float* gam; const float* bet; int cb;
  if (tid < 64) {
    float S = ps[0], SS = pss[0];
    mu = S * (1.f / 512.f);
    rstd = rsqrtf(SS * (1.f / 512.f) - mu * mu + EPSf);
    gam = sg; bet = sb; cb = tid * 8;
  } else {
    float S = ps[1] + ps[2] + ps[3], SS = pss[1] + pss[2] + pss[3];
    mu = S * (1.f / 1536.f);
    rstd = rsqrtf(SS * (1.f / 1536.f) - mu * mu + EPSf);
    gam = rg; bet = rb; cb = tid * 8 - 512;
  }
  union { unsigned short u[8]; uint4 q; } o;
  #pragma unroll
  for (int j = 0; j < 8; ++j)
    o.u[j] = f2bf((v[j] - mu) * rstd * gam[cb + j] + bet[cb + j]);
  *(uint4*)&normed[(size_t)tok * HID + tid * 8] = o.q;
}

// ---------------------------------------------------------------- low GEMM
// low2[kh][t][r] = sum_{c in half kh} cat[t][c]*dd_w[r][c]; K-split x2.
// kh=0: cat half = normed; kh=1: cat half = ybf. M=16384 N=64 K=2048 each.
// 64x64 tile, BK=64, TRIPLE-buffered (2-iteration stage lead, vmcnt(4)).
// LDS per buf (16KB): A @0, B @8192; same st_16x32 subtile swizzle.
__global__ __launch_bounds__(256) void k_gemm_low(
    const unsigned short* __restrict__ normed,
    const unsigned short* __restrict__ ybf,
    const unsigned short* __restrict__ ddw,
    float* __restrict__ low2) {
  __shared__ char lds[49152];
  int b = blockIdx.x;
  int m0 = (b >> 1) * 64;
  int kh = b & 1;
  const unsigned short* Asrc = kh ? ybf : normed;
  int tid = threadIdx.x, w = tid >> 6, l = tid & 63;
  f32x4 acc[4] = {};

  int rowS[2], colS[2];
  #pragma unroll
  for (int i = 0; i < 2; ++i) {
    int L  = i * 4096 + tid * 16;
    int sbt = L >> 10;                      // subtile 0..7
    int bb = L & 1023;
    int rr = (bb >> 6) & 15;
    rowS[i] = (sbt >> 1) * 16 + rr;
    colS[i] = (sbt & 1) * 32 + (((bb & 63) ^ ((rr >> 3) << 5)) >> 1);
  }
  int inner = (((l & 15) * 64) + ((l >> 4) * 16)) ^ (((l >> 3) & 1) << 5);
  const char* ldsp = (const char*)lds;

  auto stage = [&](int kt) {
    int bb = (kt % 3) * 16384;
    GLD16(Asrc + (size_t)(m0 + rowS[0]) * HID + kt * 64 + colS[0], lds + bb + w * 1024);
    GLD16(Asrc + (size_t)(m0 + rowS[1]) * HID + kt * 64 + colS[1], lds + bb + 4096 + w * 1024);
    GLD16(ddw + (size_t)rowS[0] * 4096 + kh * 2048 + kt * 64 + colS[0], lds + bb + 8192 + w * 1024);
    GLD16(ddw + (size_t)rowS[1] * 4096 + kh * 2048 + kt * 64 + colS[1], lds + bb + 8192 + 4096 + w * 1024);
  };

  stage(0); stage(1);                       // 8 loads in flight
  for (int kt = 0; kt < 32; ++kt) {
    // retire stage(kt); stage(kt+1) may still be in flight
    if (kt < 31) asm volatile("s_waitcnt vmcnt(4)");
    else         asm volatile("s_waitcnt vmcnt(0)");
    BAR();
    int cbase = (kt % 3) * 16384;
    bf16x8 af0 = *(const bf16x8*)(ldsp + cbase + (w * 2 + 0) * 1024 + inner);
    bf16x8 af1 = *(const bf16x8*)(ldsp + cbase + (w * 2 + 1) * 1024 + inner);
    #pragma unroll
    for (int ni = 0; ni < 4; ++ni) {
      bf16x8 b0 = *(const bf16x8*)(ldsp + cbase + 8192 + (ni * 2 + 0) * 1024 + inner);
      acc[ni] = __builtin_amdgcn_mfma_f32_16x16x32_bf16(af0, b0, acc[ni], 0, 0, 0);
    }
    #pragma unroll
    for (int ni = 0; ni < 4; ++ni) {
      bf16x8 b1 = *(const bf16x8*)(ldsp + cbase + 8192 + (ni * 2 + 1) * 1024 + inner);
      acc[ni] = __builtin_amdgcn_mfma_f32_16x16x32_bf16(af1, b1, acc[ni], 0, 0, 0);
    }
    BAR();                                  // all waves done reading buf kt%3
    if (kt + 2 < 32) stage(kt + 2);         // overwrites buf (kt+2)%3 = (kt-1)%3
  }
  float* dst = low2 + (size_t)kh * NTOK * 64;
  #pragma unroll
  for (int ni = 0; ni < 4; ++ni) {
    int row = m0 + w * 16 + ((l >> 4) * 4);
    int col = ni * 16 + (l & 15);
    #pragma unroll
    for (int rg = 0; rg < 4; ++rg)
      dst[(size_t)(row + rg) * 64 + col] = acc[ni][rg];
  }
}

// ---------------------------------------------------------------- delta + mix (sel only)
__global__ __launch_bounds__(512) void k_final(
    const float* __restrict__ hidden,
    const unsigned short* __restrict__ wysel,
    const float* __restrict__ low2,
    const float* __restrict__ A,
    const float* __restrict__ duw,
    const float* __restrict__ dub,
    float* __restrict__ out) {
  __shared__ float slow[8][64];
  int t0 = blockIdx.x * 8;
  int tid = threadIdx.x;
  {
    size_t idx = (size_t)t0 * 64 + tid;
    slow[tid >> 6][tid & 63] = low2[idx] + low2[(size_t)NTOK * 64 + idx];
  }
  __syncthreads();

  int d = tid;                              // 0..511
  float aneg = -softplus_f(A[d]);
  float dubv = dub[d];
  float wrow[64];
  #pragma unroll
  for (int r4 = 0; r4 < 16; ++r4) {
    float4 t = *(const float4*)&duw[(size_t)d * 64 + r4 * 4];
    wrow[r4 * 4 + 0] = t.x; wrow[r4 * 4 + 1] = t.y;
    wrow[r4 * 4 + 2] = t.z; wrow[r4 * 4 + 3] = t.w;
  }
  #pragma unroll 1
  for (int tk = 0; tk < 8; ++tk) {
    float acc = dubv;
    #pragma unroll
    for (int r = 0; r < 64; ++r) acc += wrow[r] * slow[tk][r];
    float delta = softplus_f(acc);
    float abar = expf(delta * aneg);
    float bbar = (abar - 1.f) / aneg;
    size_t tokb = (size_t)(t0 + tk);
    float selh = hidden[tokb * HID + d];
    float sely = bf2f(wysel[tokb * SELN + d]);
    out[tokb * HID + d] = abar * selh + bbar * sely;
  }
}

// ---------------------------------------------------------------- launch
extern "C" void kernel_launch(void* const* d_in, const int* in_sizes, int n_in,
                              void* d_out, int out_size, void* d_ws, size_t ws_size,
                              hipStream_t stream) {
  (void)in_sizes; (void)n_in; (void)out_size; (void)ws_size;
  const float* hidden = (const float*)d_in[0];
  const float* y      = (const float*)d_in[1];
  const float* A      = (const float*)d_in[2];
  const float* Ww     = (const float*)d_in[3];
  const float* ddw    = (const float*)d_in[4];
  const float* duw    = (const float*)d_in[5];
  const float* dub    = (const float*)d_in[6];
  const float* sg     = (const float*)d_in[7];
  const float* sb     = (const float*)d_in[8];
  const float* rg     = (const float*)d_in[9];
  const float* rb     = (const float*)d_in[10];
  float* out = (float*)d_out;
  char* ws = (char*)d_ws;
  // ws layout (bytes):
  unsigned short* ybf   = (unsigned short*)(ws);              //  67,108,864
  unsigned short* wbf   = (unsigned short*)(ws + 67108864);   //   8,388,608
  unsigned short* dbf   = (unsigned short*)(ws + 75497472);   //     524,288
  unsigned short* wysel = (unsigned short*)(ws + 76021760);   //  16,777,216
  unsigned short* nrm   = (unsigned short*)(ws + 92798976);   //  67,108,864
  float*          low2  = (float*)(ws + 159907840);           //   8,388,608

  hipLaunchKernelGGL(k_convert,  dim3(2048),  dim3(256), 0, stream, y, Ww, ddw, ybf, wbf, dbf);
  hipLaunchKernelGGL(k_gemm_wy,  dim3(512),   dim3(512), 0, stream, ybf, wbf, hidden, wysel, out);
  hipLaunchKernelGGL(k_ln,       dim3(16384), dim3(256), 0, stream, hidden, sg, sb, rg, rb, nrm);
  hipLaunchKernelGGL(k_gemm_low, dim3(512),   dim3(256), 0, stream, nrm, ybf, dbf, low2);
  hipLaunchKernelGGL(k_final,    dim3(2048),  dim3(512), 0, stream, hidden, wysel, low2, A, duw, dub, out);
}